// Round 1
// baseline (60.780 us; speedup 1.0000x reference)
//
#include <hip/hip_runtime.h>
#include <cstdint>
#include <cstddef>

#define S      4096   // N == M
#define BATCH  16
#define BLK    256
#define P      4                     // outer points per thread
#define OUTER_PER_BLK (BLK * P)      // 1024
#define MC     1024                  // inner chunk staged in LDS

// ---------------------------------------------------------------------------
// Pass 1: for each (role, b, outer point) compute min over an inner chunk of
//   t = |inner|^2/2 - outer . inner          (3 FMA + 1 min per pair)
// then dist^2 = 2*t + |outer|^2, combined across inner-split blocks via
// atomicMin on the uint bit pattern (valid: dist^2 clamped >= 0).
// grid = (OC * inner_split, BATCH, 2); role 0: outer=x inner=y, role 1: swap.
// ---------------------------------------------------------------------------
__global__ __launch_bounds__(BLK) void chamfer_min_kernel(
    const float* __restrict__ x, const float* __restrict__ y,
    unsigned int* __restrict__ wsmin, int inner_split)
{
    const int role = blockIdx.z;
    const int b    = blockIdx.y;
    const int ic   = blockIdx.x % inner_split;
    const int oc   = blockIdx.x / inner_split;
    const float* __restrict__ outer = (role == 0) ? x : y;
    const float* __restrict__ inner = (role == 0) ? y : x;

    const int tid      = threadIdx.x;
    const int n0       = oc * OUTER_PER_BLK;
    const int innerlen = S / inner_split;
    const int m_begin  = ic * innerlen;
    const int m_end    = m_begin + innerlen;

    __shared__ float4 lds[MC];

    // Load this thread's P outer points into registers (negated for FMA form).
    float nx0[P], nx1[P], nx2[P], xn[P], tmin[P];
#pragma unroll
    for (int p = 0; p < P; ++p) {
        const int n = n0 + p * BLK + tid;
        const float* xp = outer + ((size_t)b * S + n) * 3;
        const float a0 = xp[0], a1 = xp[1], a2 = xp[2];
        nx0[p] = -a0; nx1[p] = -a1; nx2[p] = -a2;
        xn[p]  = a0 * a0 + a1 * a1 + a2 * a2;
        tmin[p] = 3.0e38f;
    }

    for (int m0 = m_begin; m0 < m_end; m0 += MC) {
        __syncthreads();
        for (int i = tid; i < MC; i += BLK) {
            const float* yp = inner + ((size_t)b * S + m0 + i) * 3;
            const float a0 = yp[0], a1 = yp[1], a2 = yp[2];
            lds[i] = make_float4(a0, a1, a2,
                                 0.5f * (a0 * a0 + a1 * a1 + a2 * a2));
        }
        __syncthreads();

#pragma unroll 4
        for (int j = 0; j < MC; ++j) {
            const float4 v = lds[j];   // broadcast ds_read_b128
#pragma unroll
            for (int p = 0; p < P; ++p) {
                const float t = fmaf(nx0[p], v.x,
                                 fmaf(nx1[p], v.y,
                                  fmaf(nx2[p], v.z, v.w)));
                tmin[p] = fminf(tmin[p], t);
            }
        }
    }

    unsigned int* wm = wsmin + ((size_t)role * BATCH + b) * S;
#pragma unroll
    for (int p = 0; p < P; ++p) {
        const int n = n0 + p * BLK + tid;
        const float val = fmaxf(fmaf(2.0f, tmin[p], xn[p]), 0.0f); // dist^2 >= 0
        atomicMin(&wm[n], __float_as_uint(val));
    }
}

// ---------------------------------------------------------------------------
// Pass 2: per batch, mean of sqrt(min dist^2) over both directions.
// Deterministic fixed-order block reduction; writes d_out[b] directly.
// ---------------------------------------------------------------------------
__global__ __launch_bounds__(BLK) void chamfer_reduce_kernel(
    const unsigned int* __restrict__ wsmin, float* __restrict__ out)
{
    const int b = blockIdx.x;
    const int tid = threadIdx.x;
    const unsigned int* w0 = wsmin + (size_t)b * S;
    const unsigned int* w1 = wsmin + (size_t)(BATCH + b) * S;

    float s = 0.0f;
    for (int i = tid; i < S; i += BLK) {
        s += sqrtf(__uint_as_float(w0[i])) + sqrtf(__uint_as_float(w1[i]));
    }

    __shared__ float red[BLK];
    red[tid] = s;
    __syncthreads();
    for (int off = BLK / 2; off > 0; off >>= 1) {
        if (tid < off) red[tid] += red[tid + off];
        __syncthreads();
    }
    if (tid == 0) out[b] = red[0] * (0.5f / (float)S);
}

// ---------------------------------------------------------------------------
// Fallback (no workspace): each block covers the FULL inner range for its
// outer points, then atomicAdd of the partial sqrt-sum into d_out.
// ---------------------------------------------------------------------------
__global__ __launch_bounds__(BLK) void chamfer_full_kernel(
    const float* __restrict__ x, const float* __restrict__ y,
    float* __restrict__ out)
{
    const int role = blockIdx.z;
    const int b    = blockIdx.y;
    const int oc   = blockIdx.x;
    const float* __restrict__ outer = (role == 0) ? x : y;
    const float* __restrict__ inner = (role == 0) ? y : x;
    const int tid = threadIdx.x;
    const int n0  = oc * OUTER_PER_BLK;

    __shared__ float4 lds[MC];

    float nx0[P], nx1[P], nx2[P], xn[P], tmin[P];
#pragma unroll
    for (int p = 0; p < P; ++p) {
        const int n = n0 + p * BLK + tid;
        const float* xp = outer + ((size_t)b * S + n) * 3;
        const float a0 = xp[0], a1 = xp[1], a2 = xp[2];
        nx0[p] = -a0; nx1[p] = -a1; nx2[p] = -a2;
        xn[p]  = a0 * a0 + a1 * a1 + a2 * a2;
        tmin[p] = 3.0e38f;
    }

    for (int m0 = 0; m0 < S; m0 += MC) {
        __syncthreads();
        for (int i = tid; i < MC; i += BLK) {
            const float* yp = inner + ((size_t)b * S + m0 + i) * 3;
            const float a0 = yp[0], a1 = yp[1], a2 = yp[2];
            lds[i] = make_float4(a0, a1, a2,
                                 0.5f * (a0 * a0 + a1 * a1 + a2 * a2));
        }
        __syncthreads();
#pragma unroll 4
        for (int j = 0; j < MC; ++j) {
            const float4 v = lds[j];
#pragma unroll
            for (int p = 0; p < P; ++p) {
                const float t = fmaf(nx0[p], v.x,
                                 fmaf(nx1[p], v.y,
                                  fmaf(nx2[p], v.z, v.w)));
                tmin[p] = fminf(tmin[p], t);
            }
        }
    }

    float s = 0.0f;
#pragma unroll
    for (int p = 0; p < P; ++p) {
        s += sqrtf(fmaxf(fmaf(2.0f, tmin[p], xn[p]), 0.0f));
    }

    __shared__ float red[BLK];
    red[tid] = s;
    __syncthreads();
    for (int off = BLK / 2; off > 0; off >>= 1) {
        if (tid < off) red[tid] += red[tid + off];
        __syncthreads();
    }
    if (tid == 0) atomicAdd(&out[b], red[0] * (0.5f / (float)S));
}

extern "C" void kernel_launch(void* const* d_in, const int* in_sizes, int n_in,
                              void* d_out, int out_size, void* d_ws, size_t ws_size,
                              hipStream_t stream) {
    const float* x = (const float*)d_in[0];
    const float* y = (const float*)d_in[1];
    float* out = (float*)d_out;

    const size_t need = (size_t)2 * BATCH * S * sizeof(float);  // 512 KB
    if (ws_size >= need) {
        // 0x7F7F7F7F == 3.39e38f: larger than any real dist^2 -> valid +inf proxy.
        hipMemsetAsync(d_ws, 0x7F, need, stream);
        const int IS = 4;                      // inner split -> 512 blocks total
        const int OC = S / OUTER_PER_BLK;      // 4
        chamfer_min_kernel<<<dim3(OC * IS, BATCH, 2), BLK, 0, stream>>>(
            x, y, (unsigned int*)d_ws, IS);
        chamfer_reduce_kernel<<<BATCH, BLK, 0, stream>>>(
            (const unsigned int*)d_ws, out);
    } else {
        hipMemsetAsync(d_out, 0, BATCH * sizeof(float), stream);
        chamfer_full_kernel<<<dim3(S / OUTER_PER_BLK, BATCH, 2), BLK, 0, stream>>>(
            x, y, out);
    }
}